// Round 3
// baseline (196.071 us; speedup 1.0000x reference)
//
#include <hip/hip_runtime.h>
#include <hip/hip_bf16.h>
#include <hip/hip_cooperative_groups.h>

#define BB 128
#define NN 512
#define ALPHA_ 0.2f
#define NEG_INF_ -9.0e15f
#define SPB 536   // bf16 prob-row stride (hw): 268 dwords ≡ 12 mod 32 → ≤2-way conflict
#define SXW 72    // A/B fragment LDS stride (hw): 9 16B-granules ≡ 1 mod 8 → spread

namespace cg = cooperative_groups;

typedef short bf16x8 __attribute__((ext_vector_type(8)));
typedef short bf16x4v __attribute__((ext_vector_type(4)));
typedef float f32x4  __attribute__((ext_vector_type(4)));

__device__ __forceinline__ float bfs2f(unsigned short s) {
    unsigned u = ((unsigned)s) << 16;
    return __uint_as_float(u);
}

// ============================ FUSED (cooperative) ============================
// 512 blocks x 256 thr, launch_bounds(256,2): needs only 2 blocks/CU residency
// (LDS 2x36.1KB=72KB, VGPR budget 256) -> cooperative capacity check cannot fail.
// Phase 1: 2 projection tiles/block, XCD-aligned (xcd=bid&7 heuristic; correctness
//   from grid.sync fence, locality from heuristic). h1 + g=h0-h1 via LDS transpose
//   -> coalesced [f][n] stores; s1/s2 scores.
// grid.sync()
// Phase 2: 4 attention tiles/block, same XCD's b-range. adj read DIRECTLY (two
//   int4 per row-lane; no bits buffer, no cross-XCD intermediate). Softmax, diag
//   kept in MFMA, out = (att@h1 + pi*g)*inv + bias.
__global__ __launch_bounds__(256, 2) void fused(
    const float* __restrict__ x, const float* __restrict__ W, const float* __restrict__ a,
    const int* __restrict__ adj, const float* __restrict__ bias,
    __hip_bfloat16* __restrict__ h1T, __hip_bfloat16* __restrict__ gT,
    float* __restrict__ s1, float* __restrict__ s2,
    float* __restrict__ out)
{
    __shared__ __align__(16) unsigned char smem[36096];
    unsigned short* sWb0 = (unsigned short*)smem;            // [64*SXW] W0^T bf16
    unsigned short* sWb1 = sWb0 + 64 * SXW;                  // [64*SXW] W1^T bf16
    unsigned short* sX   = sWb1 + 64 * SXW;                  // x tile; later g-transpose
    unsigned short* sT   = sX   + 64 * SXW;                  // h1 transpose [f][n]
    __hip_bfloat16* sPb  = (__hip_bfloat16*)smem;            // phase-2 prob rows
    float* sInv = (float*)(smem + 34304);
    float* sPi  = (float*)(smem + 34432);

    int tid = threadIdx.x, lane = tid & 63, w = tid >> 6;
    int lane15 = lane & 15, quad = lane >> 4;
    int bid = blockIdx.x, xcd = bid & 7, slot = bid >> 3;    // slot 0..63

    // stage W transposed to bf16 B-layout (once; reused for both tiles)
    for (int idx = tid; idx < 4096; idx += 256) {
        int c = idx >> 6, f = idx & 63;
        __hip_bfloat16 b0 = __float2bfloat16(W[idx]);
        __hip_bfloat16 b1 = __float2bfloat16(W[4096 + idx]);
        sWb0[f * SXW + c] = *(unsigned short*)&b0;
        sWb1[f * SXW + c] = *(unsigned short*)&b1;
    }

    // ---- phase 1: two projection tiles ----
    #pragma unroll 1
    for (int t = 0; t < 2; ++t) {
        int tileIdx = slot * 2 + t;                          // 0..127 within this xcd
        int bk1 = 16 * xcd + (tileIdx >> 3);
        int n0  = (tileIdx & 7) << 6;
        if (t) __syncthreads();          // prior tile's sT/sX global-store reads done

        // stage x tile to bf16 A-layout: thread = (row nl = tid>>2, quarter q = tid&3)
        {
            int nl = tid >> 2, q = tid & 3;
            const float* xp = x + ((size_t)bk1 * NN + n0 + nl) * 64 + q * 16;
            float4 v0 = *(const float4*)(xp + 0);
            float4 v1 = *(const float4*)(xp + 4);
            float4 v2 = *(const float4*)(xp + 8);
            float4 v3 = *(const float4*)(xp + 12);
            union { bf16x8 v; __hip_bfloat16 h[8]; } pk0, pk1;
            pk0.h[0]=__float2bfloat16(v0.x); pk0.h[1]=__float2bfloat16(v0.y);
            pk0.h[2]=__float2bfloat16(v0.z); pk0.h[3]=__float2bfloat16(v0.w);
            pk0.h[4]=__float2bfloat16(v1.x); pk0.h[5]=__float2bfloat16(v1.y);
            pk0.h[6]=__float2bfloat16(v1.z); pk0.h[7]=__float2bfloat16(v1.w);
            pk1.h[0]=__float2bfloat16(v2.x); pk1.h[1]=__float2bfloat16(v2.y);
            pk1.h[2]=__float2bfloat16(v2.z); pk1.h[3]=__float2bfloat16(v2.w);
            pk1.h[4]=__float2bfloat16(v3.x); pk1.h[5]=__float2bfloat16(v3.y);
            pk1.h[6]=__float2bfloat16(v3.z); pk1.h[7]=__float2bfloat16(v3.w);
            *(bf16x8*)&sX[nl * SXW + q * 16]     = pk0.v;
            *(bf16x8*)&sX[nl * SXW + q * 16 + 8] = pk1.v;
        }
        __syncthreads();

        // MFMA: wave w owns m-stripe rows w*16..w*16+15; 4 n-tiles x 2 mats, K=64
        f32x4 acc0[4] = {{0,0,0,0},{0,0,0,0},{0,0,0,0},{0,0,0,0}};
        f32x4 acc1[4] = {{0,0,0,0},{0,0,0,0},{0,0,0,0},{0,0,0,0}};
        #pragma unroll
        for (int kt = 0; kt < 2; ++kt) {
            bf16x8 af = *(const bf16x8*)&sX[(w * 16 + lane15) * SXW + kt * 32 + quad * 8];
            #pragma unroll
            for (int nt = 0; nt < 4; ++nt) {
                bf16x8 b0 = *(const bf16x8*)&sWb0[(nt * 16 + lane15) * SXW + kt * 32 + quad * 8];
                acc0[nt] = __builtin_amdgcn_mfma_f32_16x16x32_bf16(af, b0, acc0[nt], 0, 0, 0);
                bf16x8 b1 = *(const bf16x8*)&sWb1[(nt * 16 + lane15) * SXW + kt * 32 + quad * 8];
                acc1[nt] = __builtin_amdgcn_mfma_f32_16x16x32_bf16(af, b1, acc1[nt], 0, 0, 0);
            }
        }
        __syncthreads();      // all waves' MFMA A-frag reads done (sX reused for g)

        // epilogue: D[m=quad*4+r][f=nt*16+lane15]; sT <- h1, sX <- g=h0-h1, scores
        float a1v[4], a2v[4];
        #pragma unroll
        for (int nt = 0; nt < 4; ++nt) {
            a1v[nt] = a[nt * 16 + lane15];
            a2v[nt] = a[64 + nt * 16 + lane15];
        }
        float p1[4] = {0, 0, 0, 0}, p2[4] = {0, 0, 0, 0};
        #pragma unroll
        for (int nt = 0; nt < 4; ++nt) {
            #pragma unroll
            for (int r = 0; r < 4; ++r) {
                int nl = w * 16 + quad * 4 + r;
                int f  = nt * 16 + lane15;
                float h0v = acc0[nt][r], h1v = acc1[nt][r];
                __hip_bfloat16 hb = __float2bfloat16(h1v);
                sT[f * 66 + nl] = *(unsigned short*)&hb;
                __hip_bfloat16 gb = __float2bfloat16(h0v - h1v);
                sX[f * 66 + nl] = *(unsigned short*)&gb;
                float hs = h0v + h1v;
                p1[r] = fmaf(hs, a1v[nt], p1[r]);
                p2[r] = fmaf(hs, a2v[nt], p2[r]);
            }
        }
        #pragma unroll
        for (int r = 0; r < 4; ++r) {
            float v1 = p1[r], v2 = p2[r];
            #pragma unroll
            for (int o = 1; o < 16; o <<= 1) {
                v1 += __shfl_xor(v1, o, 64);
                v2 += __shfl_xor(v2, o, 64);
            }
            if (lane15 == 0) {
                int row = bk1 * NN + n0 + w * 16 + quad * 4 + r;
                s1[row] = v1; s2[row] = v2;
            }
        }
        __syncthreads();
        // coalesced 128B stores: wave w writes f-rows w*16..w*16+15 of h1T and gT
        {
            unsigned short* h1Tu = (unsigned short*)h1T + (size_t)bk1 * 32768;
            unsigned short* gTu  = (unsigned short*)gT  + (size_t)bk1 * 32768;
            #pragma unroll
            for (int fr = 0; fr < 16; ++fr) {
                int f = w * 16 + fr;
                h1Tu[f * 512 + n0 + lane] = sT[f * 66 + lane];
                gTu [f * 512 + n0 + lane] = sX[f * 66 + lane];
            }
        }
    }

    cg::this_grid().sync();

    // ---- phase 2: four attention tiles, same XCD's b-range ----
    #pragma unroll 1
    for (int u = 0; u < 4; ++u) {
        int tIdx = u * 64 + slot;                            // 0..255 within this xcd
        int b  = 16 * xcd + (tIdx >> 4);
        int i0 = (tIdx & 15) << 5;
        if (u) __syncthreads();          // prior tile's sPb/sInv/sPi reads done

        const float* s2b = s2 + (size_t)b * NN;
        float4 q0 = *(const float4*)(s2b + lane * 8);
        float4 q1 = *(const float4*)(s2b + lane * 8 + 4);
        float sv[8] = {q0.x, q0.y, q0.z, q0.w, q1.x, q1.y, q1.z, q1.w};

        const float* s1p = s1 + (size_t)b * NN + i0 + 8 * w;
        float4 sA = *(const float4*)(s1p + 0);
        float4 sB = *(const float4*)(s1p + 4);
        float s1r[8] = {sA.x, sA.y, sA.z, sA.w, sB.x, sB.y, sB.z, sB.w};

        #pragma unroll
        for (int r2 = 0; r2 < 8; ++r2) {
            int r = 8 * w + r2;
            int i = i0 + r;
            float s1i = s1r[r2];
            const int* arow = adj + (size_t)i * NN + lane * 8;  // direct adj read
            int4 A0 = *(const int4*)arow;
            int4 A1 = *(const int4*)(arow + 4);
            int av[8] = {A0.x, A0.y, A0.z, A0.w, A1.x, A1.y, A1.z, A1.w};
            float p[8], ls = 0.f;
            #pragma unroll
            for (int t = 0; t < 8; ++t) {
                float s = s1i + sv[t];
                s = fmaxf(s, ALPHA_ * s);         // leaky-relu
                float e = (av[t] > 0) ? s : NEG_INF_;
                p[t] = __expf(e);                 // no max-sub; mask -> exact 0
                ls += p[t];
            }
            #pragma unroll
            for (int o = 32; o > 0; o >>= 1) ls += __shfl_xor(ls, o, 64);
            if (lane == 0) sInv[r] = 1.f / ls;
            union { bf16x8 v; __hip_bfloat16 h[8]; } pk;
            #pragma unroll
            for (int t = 0; t < 8; ++t) pk.h[t] = __float2bfloat16(p[t]);
            if (lane == (i >> 3)) sPi[r] = __bfloat162float(pk.h[r2]);  // rounded pi
            *(bf16x8*)&sPb[r * SPB + lane * 8] = pk.v;
        }
        __syncthreads();

        // MFMA: wave w = f-tile; two m-tiles (rows 0..15, 16..31) share B-frags
        int n0w = w * 16;
        int f = n0w + lane15;
        float biasf = bias[f];
        const __hip_bfloat16* bptr = h1T + (size_t)b * 32768 + (size_t)f * 512 + quad * 8;
        const __hip_bfloat16* aptr0 = &sPb[lane15 * SPB + quad * 8];
        const __hip_bfloat16* aptr1 = &sPb[(16 + lane15) * SPB + quad * 8];

        // early g loads ([f][n] layout -> two 8B vector loads), hide under MFMA
        const unsigned short* gRow = (const unsigned short*)gT + (size_t)b * 32768 + (size_t)f * 512;
        bf16x4v gv0 = *(const bf16x4v*)(gRow + i0 + quad * 4);
        bf16x4v gv1 = *(const bf16x4v*)(gRow + i0 + 16 + quad * 4);

        f32x4 acc0_ = {0, 0, 0, 0}, acc1_ = {0, 0, 0, 0};
        bf16x8 bfr[8];
        #pragma unroll
        for (int half = 0; half < 2; ++half) {
            #pragma unroll
            for (int g = 0; g < 8; ++g)
                bfr[g] = *(const bf16x8*)(bptr + (half * 8 + g) * 32);
            #pragma unroll
            for (int g = 0; g < 8; ++g) {
                int kt = half * 8 + g;
                bf16x8 a0 = *(const bf16x8*)(aptr0 + kt * 32);
                acc0_ = __builtin_amdgcn_mfma_f32_16x16x32_bf16(a0, bfr[g], acc0_, 0, 0, 0);
                bf16x8 a1 = *(const bf16x8*)(aptr1 + kt * 32);
                acc1_ = __builtin_amdgcn_mfma_f32_16x16x32_bf16(a1, bfr[g], acc1_, 0, 0, 0);
            }
        }

        // Epilogue: out = (acc + pi*g)*inv + bias  (write-only out)
        #pragma unroll
        for (int t = 0; t < 2; ++t) {
            f32x4 ac = t ? acc1_ : acc0_;
            bf16x4v gv = t ? gv1 : gv0;
            #pragma unroll
            for (int r = 0; r < 4; ++r) {
                int m = t * 16 + quad * 4 + r;
                int i = i0 + m;
                float gvf = bfs2f((unsigned short)gv[r]);
                float inv = sInv[m], pi = sPi[m];
                out[((size_t)b * NN + i) * 64 + f] = (ac[r] + pi * gvf) * inv + biasf;
            }
        }
    }
}

// ===================== FALLBACK (round-1, proven passing) ====================
__global__ __launch_bounds__(256, 4) void k1_proj(
    const float* __restrict__ x, const float* __restrict__ W, const float* __restrict__ a,
    const int* __restrict__ adj, unsigned char* __restrict__ bits,
    __hip_bfloat16* __restrict__ h1T, __hip_bfloat16* __restrict__ gN,
    float* __restrict__ s1, float* __restrict__ s2)
{
    if (blockIdx.x >= 1024) {
        int idx = (blockIdx.x - 1024) * 256 + threadIdx.x;
        const int* p = adj + (size_t)idx * 8;
        unsigned m = 0;
        #pragma unroll
        for (int t = 0; t < 8; ++t) m |= (p[t] > 0 ? 1u : 0u) << t;
        bits[idx] = (unsigned char)m;
        return;
    }
    __shared__ __align__(16) unsigned short sX[64 * SXW];
    __shared__ __align__(16) unsigned short sWb[2][64 * SXW];
    __shared__ unsigned short sT[64 * 66];
    int tid = threadIdx.x, lane = tid & 63, w = tid >> 6;
    int lane15 = lane & 15, quad = lane >> 4;
    int b = blockIdx.x >> 3, n0 = (blockIdx.x & 7) << 6;
    for (int idx = tid; idx < 4096; idx += 256) {
        int c = idx >> 6, f = idx & 63;
        __hip_bfloat16 b0 = __float2bfloat16(W[idx]);
        __hip_bfloat16 b1 = __float2bfloat16(W[4096 + idx]);
        sWb[0][f * SXW + c] = *(unsigned short*)&b0;
        sWb[1][f * SXW + c] = *(unsigned short*)&b1;
    }
    {
        int nl = tid >> 2, q = tid & 3;
        const float* xp = x + ((size_t)b * NN + n0 + nl) * 64 + q * 16;
        float4 v0 = *(const float4*)(xp + 0);
        float4 v1 = *(const float4*)(xp + 4);
        float4 v2 = *(const float4*)(xp + 8);
        float4 v3 = *(const float4*)(xp + 12);
        union { bf16x8 v; __hip_bfloat16 h[8]; } pk0, pk1;
        pk0.h[0]=__float2bfloat16(v0.x); pk0.h[1]=__float2bfloat16(v0.y);
        pk0.h[2]=__float2bfloat16(v0.z); pk0.h[3]=__float2bfloat16(v0.w);
        pk0.h[4]=__float2bfloat16(v1.x); pk0.h[5]=__float2bfloat16(v1.y);
        pk0.h[6]=__float2bfloat16(v1.z); pk0.h[7]=__float2bfloat16(v1.w);
        pk1.h[0]=__float2bfloat16(v2.x); pk1.h[1]=__float2bfloat16(v2.y);
        pk1.h[2]=__float2bfloat16(v2.z); pk1.h[3]=__float2bfloat16(v2.w);
        pk1.h[4]=__float2bfloat16(v3.x); pk1.h[5]=__float2bfloat16(v3.y);
        pk1.h[6]=__float2bfloat16(v3.z); pk1.h[7]=__float2bfloat16(v3.w);
        *(bf16x8*)&sX[nl * SXW + q * 16]     = pk0.v;
        *(bf16x8*)&sX[nl * SXW + q * 16 + 8] = pk1.v;
    }
    __syncthreads();
    f32x4 acc0[4] = {{0,0,0,0},{0,0,0,0},{0,0,0,0},{0,0,0,0}};
    f32x4 acc1[4] = {{0,0,0,0},{0,0,0,0},{0,0,0,0},{0,0,0,0}};
    #pragma unroll
    for (int kt = 0; kt < 2; ++kt) {
        bf16x8 af = *(const bf16x8*)&sX[(w * 16 + lane15) * SXW + kt * 32 + quad * 8];
        #pragma unroll
        for (int nt = 0; nt < 4; ++nt) {
            bf16x8 b0 = *(const bf16x8*)&sWb[0][(nt * 16 + lane15) * SXW + kt * 32 + quad * 8];
            acc0[nt] = __builtin_amdgcn_mfma_f32_16x16x32_bf16(af, b0, acc0[nt], 0, 0, 0);
            bf16x8 b1 = *(const bf16x8*)&sWb[1][(nt * 16 + lane15) * SXW + kt * 32 + quad * 8];
            acc1[nt] = __builtin_amdgcn_mfma_f32_16x16x32_bf16(af, b1, acc1[nt], 0, 0, 0);
        }
    }
    float a1v[4], a2v[4];
    #pragma unroll
    for (int nt = 0; nt < 4; ++nt) {
        a1v[nt] = a[nt * 16 + lane15];
        a2v[nt] = a[64 + nt * 16 + lane15];
    }
    float p1[4] = {0, 0, 0, 0}, p2[4] = {0, 0, 0, 0};
    unsigned short* gNu = (unsigned short*)gN + (size_t)b * 32768 + (size_t)n0 * 64;
    #pragma unroll
    for (int nt = 0; nt < 4; ++nt) {
        #pragma unroll
        for (int r = 0; r < 4; ++r) {
            int nl = w * 16 + quad * 4 + r;
            int f  = nt * 16 + lane15;
            float h0v = acc0[nt][r], h1v = acc1[nt][r];
            __hip_bfloat16 hb = __float2bfloat16(h1v);
            sT[f * 66 + nl] = *(unsigned short*)&hb;
            __hip_bfloat16 gb16 = __float2bfloat16(h0v - h1v);
            gNu[(size_t)nl * 64 + f] = *(unsigned short*)&gb16;
            float hs = h0v + h1v;
            p1[r] = fmaf(hs, a1v[nt], p1[r]);
            p2[r] = fmaf(hs, a2v[nt], p2[r]);
        }
    }
    #pragma unroll
    for (int r = 0; r < 4; ++r) {
        float v1 = p1[r], v2 = p2[r];
        #pragma unroll
        for (int o = 1; o < 16; o <<= 1) {
            v1 += __shfl_xor(v1, o, 64);
            v2 += __shfl_xor(v2, o, 64);
        }
        if (lane15 == 0) {
            int row = b * NN + n0 + w * 16 + quad * 4 + r;
            s1[row] = v1; s2[row] = v2;
        }
    }
    __syncthreads();
    unsigned short* h1Tu = (unsigned short*)h1T;
    #pragma unroll
    for (int fr = 0; fr < 16; ++fr) {
        int f = w * 16 + fr;
        h1Tu[(size_t)b * 32768 + f * 512 + n0 + lane] = sT[f * 66 + lane];
    }
}

__global__ __launch_bounds__(256, 4) void k2_att(
    const unsigned char* __restrict__ adjbits,
    const float* __restrict__ bias,
    const __hip_bfloat16* __restrict__ h1T,
    const __hip_bfloat16* __restrict__ gN,
    const float* __restrict__ s1, const float* __restrict__ s2,
    float* __restrict__ out)
{
    __shared__ __align__(16) __hip_bfloat16 sPb[32 * SPB];
    __shared__ float sInv[32], sPi[32];
    int tid = threadIdx.x, w = tid >> 6, lane = tid & 63;
    int F = blockIdx.x;
    int work = (F & 7) * 256 + (F >> 3);
    int b = work >> 4;
    int i0 = (work & 15) << 5;
    const float* s2b = s2 + (size_t)b * NN;
    float4 q0 = *(const float4*)(s2b + lane * 8);
    float4 q1 = *(const float4*)(s2b + lane * 8 + 4);
    float sv[8] = {q0.x, q0.y, q0.z, q0.w, q1.x, q1.y, q1.z, q1.w};
    const float* s1p = s1 + (size_t)b * NN + i0 + 8 * w;
    float4 sA = *(const float4*)(s1p + 0);
    float4 sB = *(const float4*)(s1p + 4);
    float s1r[8] = {sA.x, sA.y, sA.z, sA.w, sB.x, sB.y, sB.z, sB.w};
    #pragma unroll
    for (int r2 = 0; r2 < 8; ++r2) {
        int r = 8 * w + r2;
        int i = i0 + r;
        float s1i = s1r[r2];
        unsigned mb = adjbits[(size_t)i * 64 + lane];
        float p[8], ls = 0.f;
        #pragma unroll
        for (int t = 0; t < 8; ++t) {
            float s = s1i + sv[t];
            s = fmaxf(s, ALPHA_ * s);
            float e = (mb & (1u << t)) ? s : NEG_INF_;
            p[t] = __expf(e);
            ls += p[t];
        }
        #pragma unroll
        for (int o = 32; o > 0; o >>= 1) ls += __shfl_xor(ls, o, 64);
        if (lane == 0) sInv[r] = 1.f / ls;
        union { bf16x8 v; __hip_bfloat16 h[8]; } pk;
        #pragma unroll
        for (int t = 0; t < 8; ++t) pk.h[t] = __float2bfloat16(p[t]);
        if (lane == (i >> 3)) sPi[r] = __bfloat162float(pk.h[r2]);
        *(bf16x8*)&sPb[r * SPB + lane * 8] = pk.v;
    }
    __syncthreads();
    int lane15 = lane & 15, quad = lane >> 4;
    int n0w = w * 16;
    int f = n0w + lane15;
    float biasf = bias[f];
    const __hip_bfloat16* bptr = h1T + (size_t)b * 32768 + (size_t)f * 512 + quad * 8;
    const __hip_bfloat16* aptr0 = &sPb[lane15 * SPB + quad * 8];
    const __hip_bfloat16* aptr1 = &sPb[(16 + lane15) * SPB + quad * 8];
    const unsigned short* gb = (const unsigned short*)gN + (size_t)b * 32768 + f;
    unsigned short gvw[8];
    #pragma unroll
    for (int t = 0; t < 2; ++t) {
        #pragma unroll
        for (int r = 0; r < 4; ++r)
            gvw[t * 4 + r] = gb[(size_t)(i0 + t * 16 + quad * 4 + r) * 64];
    }
    f32x4 acc0 = {0, 0, 0, 0}, acc1 = {0, 0, 0, 0};
    bf16x8 bfr[8];
    #pragma unroll
    for (int half = 0; half < 2; ++half) {
        #pragma unroll
        for (int g = 0; g < 8; ++g)
            bfr[g] = *(const bf16x8*)(bptr + (half * 8 + g) * 32);
        #pragma unroll
        for (int g = 0; g < 8; ++g) {
            int kt = half * 8 + g;
            bf16x8 a0 = *(const bf16x8*)(aptr0 + kt * 32);
            acc0 = __builtin_amdgcn_mfma_f32_16x16x32_bf16(a0, bfr[g], acc0, 0, 0, 0);
            bf16x8 a1 = *(const bf16x8*)(aptr1 + kt * 32);
            acc1 = __builtin_amdgcn_mfma_f32_16x16x32_bf16(a1, bfr[g], acc1, 0, 0, 0);
        }
    }
    #pragma unroll
    for (int t = 0; t < 2; ++t) {
        f32x4 ac = t ? acc1 : acc0;
        #pragma unroll
        for (int r = 0; r < 4; ++r) {
            int m = t * 16 + quad * 4 + r;
            int i = i0 + m;
            float gvf = bfs2f(gvw[t * 4 + r]);
            float inv = sInv[m], pi = sPi[m];
            out[((size_t)b * NN + i) * 64 + f] = (ac[r] + pi * gvf) * inv + biasf;
        }
    }
}

extern "C" void kernel_launch(void* const* d_in, const int* in_sizes, int n_in,
                              void* d_out, int out_size, void* d_ws, size_t ws_size,
                              hipStream_t stream) {
    const void* p_x = nullptr; const void* p_adj = nullptr; const void* p_W = nullptr;
    const void* p_a = nullptr; const void* p_bias = nullptr;
    for (int k = 0; k < n_in; ++k) {
        switch (in_sizes[k]) {
            case 128 * 512 * 64: p_x    = d_in[k]; break;
            case 512 * 512:      p_adj  = d_in[k]; break;
            case 2 * 64 * 64:    p_W    = d_in[k]; break;
            case 2 * 64:         p_a    = d_in[k]; break;
            case 64:             p_bias = d_in[k]; break;
        }
    }
    const float* x    = (const float*)p_x;
    const int*   adj  = (const int*)p_adj;
    const float* W    = (const float*)p_W;
    const float* a    = (const float*)p_a;
    const float* bias = (const float*)p_bias;
    float* out = (float*)d_out;

    // ws (16.8 MB): h1T bf16 8MB | gT bf16 8MB | s1 256KB | s2 256KB | bits 32KB
    __hip_bfloat16* h1T = (__hip_bfloat16*)d_ws;
    __hip_bfloat16* gT  = h1T + 4194304;
    float* s1 = (float*)(gT + 4194304);
    float* s2 = s1 + 65536;
    unsigned char* bits = (unsigned char*)(s2 + 65536);

    void* args[] = { (void*)&x, (void*)&W, (void*)&a, (void*)&adj, (void*)&bias,
                     (void*)&h1T, (void*)&gT, (void*)&s1, (void*)&s2, (void*)&out };
    hipError_t e = hipLaunchCooperativeKernel((const void*)fused, dim3(512), dim3(256),
                                              args, 0, stream);
    if (e != hipSuccess) {
        // fallback: proven round-1 two-kernel path (gN natural layout)
        k1_proj<<<dim3(BB * 8 + 128), 256, 0, stream>>>(x, W, a, adj, bits, h1T, gT, s1, s2);
        k2_att<<<dim3(BB * NN / 32), 256, 0, stream>>>(bits, bias, h1T, gT, s1, s2, out);
    }
}

// Round 4
// 109.571 us; speedup vs baseline: 1.7894x; 1.7894x over previous
//
#include <hip/hip_runtime.h>
#include <hip/hip_bf16.h>

#define BB 128
#define NN 512
#define ALPHA_ 0.2f
#define NEG_INF_ -9.0e15f
#define SPB 536   // bf16 prob-row stride (hw): 268 dwords ≡ 12 mod 32 → ≤2-way conflict
#define SXW 72    // A/B fragment LDS stride (hw): 9 16B-granules ≡ 1 mod 8 → spread

typedef short bf16x8 __attribute__((ext_vector_type(8)));
typedef float f32x4  __attribute__((ext_vector_type(4)));

__device__ __forceinline__ float bfs2f(unsigned short s) {
    unsigned u = ((unsigned)s) << 16;
    return __uint_as_float(u);
}

// k1 (MFMA): 1024 blocks = (b, 64-node tile) projection, 4 clean rounds at 4 blk/CU.
// x loads hoisted first (HBM-cold latency hides under W staging/convert).
// W staged via float4 loads + transposed LDS scatter. h1 -> LDS transpose ->
// h1T[b][f][n] bf16 (coalesced); g = h0-h1 -> natural [i][f] bf16 direct store.
// Scores reduced with ONE packed 4-stage butterfly (chain 4, not 16).
__global__ __launch_bounds__(256, 4) void k1_proj(
    const float* __restrict__ x, const float* __restrict__ W, const float* __restrict__ a,
    __hip_bfloat16* __restrict__ h1T, __hip_bfloat16* __restrict__ gN,
    float* __restrict__ s1, float* __restrict__ s2)
{
    __shared__ __align__(16) unsigned short sX[64 * SXW];       // x tile, A-layout [n_local][c]
    __shared__ __align__(16) unsigned short sWb[2][64 * SXW];   // W^T, B-layout [f][c]
    __shared__ unsigned short sT[64 * 66];                      // transpose buf [f][n_local]
    int tid = threadIdx.x, lane = tid & 63, w = tid >> 6;
    int lane15 = lane & 15, quad = lane >> 4;
    int b = blockIdx.x >> 3, n0 = (blockIdx.x & 7) << 6;

    // hoist x tile loads (cold HBM) — issue before W staging so latency overlaps
    int nl = tid >> 2, q = tid & 3;
    const float* xp = x + ((size_t)b * NN + n0 + nl) * 64 + q * 16;
    float4 v0 = *(const float4*)(xp + 0);
    float4 v1 = *(const float4*)(xp + 4);
    float4 v2 = *(const float4*)(xp + 8);
    float4 v3 = *(const float4*)(xp + 12);

    // stage W transposed to bf16 B-layout: float4 loads + 2B transposed scatter
    #pragma unroll
    for (int it = 0; it < 4; ++it) {
        int e  = tid + it * 256;          // float4 index within one matrix, 0..1023
        int c  = e >> 4;                  // 0..63
        int f0 = (e & 15) << 2;           // 0,4,...,60
        float4 w0 = *(const float4*)(W + c * 64 + f0);
        float4 w1 = *(const float4*)(W + 4096 + c * 64 + f0);
        __hip_bfloat16 t0;
        t0 = __float2bfloat16(w0.x); sWb[0][(f0 + 0) * SXW + c] = *(unsigned short*)&t0;
        t0 = __float2bfloat16(w0.y); sWb[0][(f0 + 1) * SXW + c] = *(unsigned short*)&t0;
        t0 = __float2bfloat16(w0.z); sWb[0][(f0 + 2) * SXW + c] = *(unsigned short*)&t0;
        t0 = __float2bfloat16(w0.w); sWb[0][(f0 + 3) * SXW + c] = *(unsigned short*)&t0;
        t0 = __float2bfloat16(w1.x); sWb[1][(f0 + 0) * SXW + c] = *(unsigned short*)&t0;
        t0 = __float2bfloat16(w1.y); sWb[1][(f0 + 1) * SXW + c] = *(unsigned short*)&t0;
        t0 = __float2bfloat16(w1.z); sWb[1][(f0 + 2) * SXW + c] = *(unsigned short*)&t0;
        t0 = __float2bfloat16(w1.w); sWb[1][(f0 + 3) * SXW + c] = *(unsigned short*)&t0;
    }
    // pack x tile to bf16 A-layout
    {
        union { bf16x8 v; __hip_bfloat16 h[8]; } pk0, pk1;
        pk0.h[0]=__float2bfloat16(v0.x); pk0.h[1]=__float2bfloat16(v0.y);
        pk0.h[2]=__float2bfloat16(v0.z); pk0.h[3]=__float2bfloat16(v0.w);
        pk0.h[4]=__float2bfloat16(v1.x); pk0.h[5]=__float2bfloat16(v1.y);
        pk0.h[6]=__float2bfloat16(v1.z); pk0.h[7]=__float2bfloat16(v1.w);
        pk1.h[0]=__float2bfloat16(v2.x); pk1.h[1]=__float2bfloat16(v2.y);
        pk1.h[2]=__float2bfloat16(v2.z); pk1.h[3]=__float2bfloat16(v2.w);
        pk1.h[4]=__float2bfloat16(v3.x); pk1.h[5]=__float2bfloat16(v3.y);
        pk1.h[6]=__float2bfloat16(v3.z); pk1.h[7]=__float2bfloat16(v3.w);
        *(bf16x8*)&sX[nl * SXW + q * 16]     = pk0.v;
        *(bf16x8*)&sX[nl * SXW + q * 16 + 8] = pk1.v;
    }
    __syncthreads();

    // MFMA: wave w owns m-stripe rows w*16..w*16+15; 4 n-tiles x 2 mats, K=64
    f32x4 acc0[4] = {{0,0,0,0},{0,0,0,0},{0,0,0,0},{0,0,0,0}};
    f32x4 acc1[4] = {{0,0,0,0},{0,0,0,0},{0,0,0,0},{0,0,0,0}};
    #pragma unroll
    for (int kt = 0; kt < 2; ++kt) {
        bf16x8 af = *(const bf16x8*)&sX[(w * 16 + lane15) * SXW + kt * 32 + quad * 8];
        #pragma unroll
        for (int nt = 0; nt < 4; ++nt) {
            bf16x8 b0 = *(const bf16x8*)&sWb[0][(nt * 16 + lane15) * SXW + kt * 32 + quad * 8];
            acc0[nt] = __builtin_amdgcn_mfma_f32_16x16x32_bf16(af, b0, acc0[nt], 0, 0, 0);
            bf16x8 b1 = *(const bf16x8*)&sWb[1][(nt * 16 + lane15) * SXW + kt * 32 + quad * 8];
            acc1[nt] = __builtin_amdgcn_mfma_f32_16x16x32_bf16(af, b1, acc1[nt], 0, 0, 0);
        }
    }

    // epilogue: D[m = quad*4+r][f = nt*16+lane15]; sT <- h1, gN <- h0-h1, scores
    float a1v[4], a2v[4];
    #pragma unroll
    for (int nt = 0; nt < 4; ++nt) {
        a1v[nt] = a[nt * 16 + lane15];
        a2v[nt] = a[64 + nt * 16 + lane15];
    }
    float p1[4] = {0, 0, 0, 0}, p2[4] = {0, 0, 0, 0};
    unsigned short* gNu = (unsigned short*)gN + (size_t)b * 32768 + (size_t)n0 * 64;
    #pragma unroll
    for (int nt = 0; nt < 4; ++nt) {
        #pragma unroll
        for (int r = 0; r < 4; ++r) {
            int nlr = w * 16 + quad * 4 + r;
            int f   = nt * 16 + lane15;
            float h0v = acc0[nt][r], h1v = acc1[nt][r];
            __hip_bfloat16 hb = __float2bfloat16(h1v);
            sT[f * 66 + nlr] = *(unsigned short*)&hb;
            __hip_bfloat16 gb16 = __float2bfloat16(h0v - h1v);
            gNu[(size_t)nlr * 64 + f] = *(unsigned short*)&gb16;
            float hs = h0v + h1v;
            p1[r] = fmaf(hs, a1v[nt], p1[r]);
            p2[r] = fmaf(hs, a2v[nt], p2[r]);
        }
    }
    // packed butterfly: 4-stage chain, 8 independent adds per stage
    #pragma unroll
    for (int o = 1; o < 16; o <<= 1) {
        #pragma unroll
        for (int r = 0; r < 4; ++r) {
            p1[r] += __shfl_xor(p1[r], o, 64);
            p2[r] += __shfl_xor(p2[r], o, 64);
        }
    }
    if (lane15 == 0) {
        #pragma unroll
        for (int r = 0; r < 4; ++r) {
            int row = b * NN + n0 + w * 16 + quad * 4 + r;
            s1[row] = p1[r]; s2[row] = p2[r];
        }
    }
    __syncthreads();
    // h1T: wave w writes f-rows w*16..w*16+15, 128B contiguous
    unsigned short* h1Tu = (unsigned short*)h1T;
    #pragma unroll
    for (int fr = 0; fr < 16; ++fr) {
        int f = w * 16 + fr;
        h1Tu[(size_t)b * 32768 + f * 512 + n0 + lane] = sT[f * 66 + lane];
    }
}

// k2: 2048 blocks, XCD-chunked swizzle. Block = (b, 32 rows). adj read DIRECTLY
// (2 x int4/row-lane, coalesced, L2-resident — no bits pre-pass). Latency plan:
// g scalars + first-8 B-frags issued BEFORE softmax (fly under ~1µs of VALU);
// second-8 B-frags issued before MFMA half 0 (fly under it). Softmax row loop has
// no cross-iteration deps; row sums ls[8] reduced by ONE packed 6-stage butterfly.
// Diag prob kept in MFMA; out = (att@h1 + pi*(h0-h1))*inv + bias, write-only.
__global__ __launch_bounds__(256, 4) void k2_att(
    const int* __restrict__ adj,
    const float* __restrict__ bias,
    const __hip_bfloat16* __restrict__ h1T,
    const __hip_bfloat16* __restrict__ gN,
    const float* __restrict__ s1, const float* __restrict__ s2,
    float* __restrict__ out)
{
    __shared__ __align__(16) __hip_bfloat16 sPb[32 * SPB];   // 34.3 KB
    __shared__ float sInv[32], sPi[32];
    int tid = threadIdx.x, w = tid >> 6, lane = tid & 63;
    int F = blockIdx.x;
    int work = (F & 7) * 256 + (F >> 3);     // bijective (2048 % 8 == 0)
    int b = work >> 4;
    int i0 = (work & 15) << 5;
    int lane15 = lane & 15, quad = lane >> 4;
    int f = w * 16 + lane15;

    // ---- issue all long-latency loads first ----
    const float* s2b = s2 + (size_t)b * NN;
    float4 q0 = *(const float4*)(s2b + lane * 8);
    float4 q1 = *(const float4*)(s2b + lane * 8 + 4);
    const float* s1p = s1 + (size_t)b * NN + i0 + 8 * w;
    float4 sA = *(const float4*)(s1p + 0);
    float4 sB = *(const float4*)(s1p + 4);
    // g scalars (semi-coalesced 32B/16-lane segments)
    const unsigned short* gb = (const unsigned short*)gN + (size_t)b * 32768 + f;
    unsigned short gvw[8];
    #pragma unroll
    for (int t = 0; t < 2; ++t)
        #pragma unroll
        for (int r = 0; r < 4; ++r)
            gvw[t * 4 + r] = gb[(size_t)(i0 + t * 16 + quad * 4 + r) * 64];
    // first-half B-frags: latency hides under the whole softmax phase
    const __hip_bfloat16* bptr = h1T + (size_t)b * 32768 + (size_t)f * 512 + quad * 8;
    bf16x8 bfr0[8];
    #pragma unroll
    for (int g = 0; g < 8; ++g)
        bfr0[g] = *(const bf16x8*)(bptr + g * 32);

    float sv[8] = {q0.x, q0.y, q0.z, q0.w, q1.x, q1.y, q1.z, q1.w};
    float s1r[8] = {sA.x, sA.y, sA.z, sA.w, sB.x, sB.y, sB.z, sB.w};

    // ---- softmax: no cross-row deps in loop; one packed butterfly after ----
    float ls[8];
    #pragma unroll
    for (int r2 = 0; r2 < 8; ++r2) {
        int r = 8 * w + r2;
        int i = i0 + r;
        float s1i = s1r[r2];
        const int* arow = adj + (size_t)i * NN + lane * 8;   // 32B/lane, coalesced
        int4 A0 = *(const int4*)arow;
        int4 A1 = *(const int4*)(arow + 4);
        int av[8] = {A0.x, A0.y, A0.z, A0.w, A1.x, A1.y, A1.z, A1.w};
        float p[8], l = 0.f;
        #pragma unroll
        for (int t = 0; t < 8; ++t) {
            float s = s1i + sv[t];
            s = fmaxf(s, ALPHA_ * s);             // leaky-relu
            float e = (av[t] > 0) ? s : NEG_INF_;
            p[t] = __expf(e);                     // no max-sub; mask -> exact 0
            l += p[t];
        }
        ls[r2] = l;
        union { bf16x8 v; __hip_bfloat16 h[8]; } pk;
        #pragma unroll
        for (int t = 0; t < 8; ++t) pk.h[t] = __float2bfloat16(p[t]);
        if (lane == (i >> 3)) sPi[r] = __bfloat162float(pk.h[r2]);  // rounded pi
        *(bf16x8*)&sPb[r * SPB + lane * 8] = pk.v;
    }
    #pragma unroll
    for (int o = 32; o > 0; o >>= 1) {
        #pragma unroll
        for (int r2 = 0; r2 < 8; ++r2) ls[r2] += __shfl_xor(ls[r2], o, 64);
    }
    if (lane == 0) {
        #pragma unroll
        for (int r2 = 0; r2 < 8; ++r2) sInv[8 * w + r2] = 1.f / ls[r2];
    }
    __syncthreads();

    // ---- MFMA: wave w = f-tile; two m-tiles share B-frags ----
    const __hip_bfloat16* aptr0 = &sPb[lane15 * SPB + quad * 8];
    const __hip_bfloat16* aptr1 = &sPb[(16 + lane15) * SPB + quad * 8];
    // second-half B-frags: latency hides under MFMA half 0
    bf16x8 bfr1[8];
    #pragma unroll
    for (int g = 0; g < 8; ++g)
        bfr1[g] = *(const bf16x8*)(bptr + (8 + g) * 32);

    f32x4 acc0 = {0, 0, 0, 0}, acc1 = {0, 0, 0, 0};
    #pragma unroll
    for (int g = 0; g < 8; ++g) {
        bf16x8 a0 = *(const bf16x8*)(aptr0 + g * 32);
        acc0 = __builtin_amdgcn_mfma_f32_16x16x32_bf16(a0, bfr0[g], acc0, 0, 0, 0);
        bf16x8 a1 = *(const bf16x8*)(aptr1 + g * 32);
        acc1 = __builtin_amdgcn_mfma_f32_16x16x32_bf16(a1, bfr0[g], acc1, 0, 0, 0);
    }
    #pragma unroll
    for (int g = 0; g < 8; ++g) {
        int kt = 8 + g;
        bf16x8 a0 = *(const bf16x8*)(aptr0 + kt * 32);
        acc0 = __builtin_amdgcn_mfma_f32_16x16x32_bf16(a0, bfr1[g], acc0, 0, 0, 0);
        bf16x8 a1 = *(const bf16x8*)(aptr1 + kt * 32);
        acc1 = __builtin_amdgcn_mfma_f32_16x16x32_bf16(a1, bfr1[g], acc1, 0, 0, 0);
    }

    // Epilogue: out = (acc + pi*g)*inv + bias  (write-only out)
    float biasf = bias[f];
    #pragma unroll
    for (int t = 0; t < 2; ++t) {
        f32x4 ac = t ? acc1 : acc0;
        #pragma unroll
        for (int r = 0; r < 4; ++r) {
            int m = t * 16 + quad * 4 + r;
            int i = i0 + m;
            float gvf = bfs2f(gvw[t * 4 + r]);
            float inv = sInv[m], pi = sPi[m];
            out[((size_t)b * NN + i) * 64 + f] = (ac[r] + pi * gvf) * inv + biasf;
        }
    }
}

extern "C" void kernel_launch(void* const* d_in, const int* in_sizes, int n_in,
                              void* d_out, int out_size, void* d_ws, size_t ws_size,
                              hipStream_t stream) {
    const void* p_x = nullptr; const void* p_adj = nullptr; const void* p_W = nullptr;
    const void* p_a = nullptr; const void* p_bias = nullptr;
    for (int k = 0; k < n_in; ++k) {
        switch (in_sizes[k]) {
            case 128 * 512 * 64: p_x    = d_in[k]; break;
            case 512 * 512:      p_adj  = d_in[k]; break;
            case 2 * 64 * 64:    p_W    = d_in[k]; break;
            case 2 * 64:         p_a    = d_in[k]; break;
            case 64:             p_bias = d_in[k]; break;
        }
    }
    const float* x    = (const float*)p_x;
    const int*   adj  = (const int*)p_adj;
    const float* W    = (const float*)p_W;
    const float* a    = (const float*)p_a;
    const float* bias = (const float*)p_bias;
    float* out = (float*)d_out;

    // ws (16.5 MB): h1T bf16 8MB | gN bf16 8MB | s1 256KB | s2 256KB
    __hip_bfloat16* h1T = (__hip_bfloat16*)d_ws;
    __hip_bfloat16* gN  = h1T + 4194304;
    float* s1 = (float*)(gN + 4194304);
    float* s2 = s1 + 65536;

    k1_proj<<<dim3(BB * 8), 256, 0, stream>>>(x, W, a, h1T, gN, s1, s2);
    k2_att<<<dim3(BB * NN / 32), 256, 0, stream>>>(adj, bias, h1T, gN, s1, s2, out);
}

// Round 5
// 106.953 us; speedup vs baseline: 1.8332x; 1.0245x over previous
//
#include <hip/hip_runtime.h>
#include <hip/hip_bf16.h>

#define BB 128
#define NN 512
#define ALPHA_ 0.2f
#define NEG_INF_ -9.0e15f
#define SPB 536   // bf16 prob-row stride (hw): 268 dwords ≡ 12 mod 32 → ≤2-way conflict
#define SXW 72    // A/B fragment LDS stride (hw): 9 16B-granules ≡ 1 mod 8 → spread

typedef short bf16x8 __attribute__((ext_vector_type(8)));
typedef float f32x4  __attribute__((ext_vector_type(4)));

__device__ __forceinline__ float bfs2f(unsigned short s) {
    unsigned u = ((unsigned)s) << 16;
    return __uint_as_float(u);
}

// k1 (MFMA): 1024 blocks = (b, 64-node tile), 4 clean dispatch rounds at 4 blk/CU.
// Folded bits pass: block bid packs bits[bid*32 .. +32) (32 thr, 1KB contiguous read)
// — no extra blocks, no tail. x loads hoisted first (cold-HBM latency hides under
// W staging). h1 -> LDS transpose -> h1T[b][f][n] bf16 (coalesced); g = h0-h1 ->
// natural [i][f] bf16 direct store. Scores: ONE packed 4-stage butterfly.
__global__ __launch_bounds__(256, 4) void k1_proj(
    const float* __restrict__ x, const float* __restrict__ W, const float* __restrict__ a,
    const int* __restrict__ adj, unsigned char* __restrict__ bits,
    __hip_bfloat16* __restrict__ h1T, __hip_bfloat16* __restrict__ gN,
    float* __restrict__ s1, float* __restrict__ s2)
{
    __shared__ __align__(16) unsigned short sX[64 * SXW];       // x tile, A-layout [n_local][c]
    __shared__ __align__(16) unsigned short sWb[2][64 * SXW];   // W^T, B-layout [f][c]
    __shared__ unsigned short sT[64 * 66];                      // transpose buf [f][n_local]
    int tid = threadIdx.x, lane = tid & 63, w = tid >> 6;
    int lane15 = lane & 15, quad = lane >> 4;
    int b = blockIdx.x >> 3, n0 = (blockIdx.x & 7) << 6;

    // hoist x tile loads (cold HBM) — issue before W staging so latency overlaps
    int nl = tid >> 2, q = tid & 3;
    const float* xp = x + ((size_t)b * NN + n0 + nl) * 64 + q * 16;
    float4 v0 = *(const float4*)(xp + 0);
    float4 v1 = *(const float4*)(xp + 4);
    float4 v2 = *(const float4*)(xp + 8);
    float4 v3 = *(const float4*)(xp + 12);

    // folded bits pass: this block owns bits[bid*32 .. bid*32+32)
    if (tid < 32) {
        int idx = blockIdx.x * 32 + tid;
        const int* p = adj + (size_t)idx * 8;
        unsigned m = 0;
        #pragma unroll
        for (int t = 0; t < 8; ++t) m |= (p[t] > 0 ? 1u : 0u) << t;
        bits[idx] = (unsigned char)m;
    }

    // stage W transposed to bf16 B-layout: float4 loads + 2B transposed scatter
    #pragma unroll
    for (int it = 0; it < 4; ++it) {
        int e  = tid + it * 256;          // float4 index within one matrix, 0..1023
        int c  = e >> 4;                  // 0..63
        int f0 = (e & 15) << 2;           // 0,4,...,60
        float4 w0 = *(const float4*)(W + c * 64 + f0);
        float4 w1 = *(const float4*)(W + 4096 + c * 64 + f0);
        __hip_bfloat16 t0;
        t0 = __float2bfloat16(w0.x); sWb[0][(f0 + 0) * SXW + c] = *(unsigned short*)&t0;
        t0 = __float2bfloat16(w0.y); sWb[0][(f0 + 1) * SXW + c] = *(unsigned short*)&t0;
        t0 = __float2bfloat16(w0.z); sWb[0][(f0 + 2) * SXW + c] = *(unsigned short*)&t0;
        t0 = __float2bfloat16(w0.w); sWb[0][(f0 + 3) * SXW + c] = *(unsigned short*)&t0;
        t0 = __float2bfloat16(w1.x); sWb[1][(f0 + 0) * SXW + c] = *(unsigned short*)&t0;
        t0 = __float2bfloat16(w1.y); sWb[1][(f0 + 1) * SXW + c] = *(unsigned short*)&t0;
        t0 = __float2bfloat16(w1.z); sWb[1][(f0 + 2) * SXW + c] = *(unsigned short*)&t0;
        t0 = __float2bfloat16(w1.w); sWb[1][(f0 + 3) * SXW + c] = *(unsigned short*)&t0;
    }
    // pack x tile to bf16 A-layout
    {
        union { bf16x8 v; __hip_bfloat16 h[8]; } pk0, pk1;
        pk0.h[0]=__float2bfloat16(v0.x); pk0.h[1]=__float2bfloat16(v0.y);
        pk0.h[2]=__float2bfloat16(v0.z); pk0.h[3]=__float2bfloat16(v0.w);
        pk0.h[4]=__float2bfloat16(v1.x); pk0.h[5]=__float2bfloat16(v1.y);
        pk0.h[6]=__float2bfloat16(v1.z); pk0.h[7]=__float2bfloat16(v1.w);
        pk1.h[0]=__float2bfloat16(v2.x); pk1.h[1]=__float2bfloat16(v2.y);
        pk1.h[2]=__float2bfloat16(v2.z); pk1.h[3]=__float2bfloat16(v2.w);
        pk1.h[4]=__float2bfloat16(v3.x); pk1.h[5]=__float2bfloat16(v3.y);
        pk1.h[6]=__float2bfloat16(v3.z); pk1.h[7]=__float2bfloat16(v3.w);
        *(bf16x8*)&sX[nl * SXW + q * 16]     = pk0.v;
        *(bf16x8*)&sX[nl * SXW + q * 16 + 8] = pk1.v;
    }
    __syncthreads();

    // MFMA: wave w owns m-stripe rows w*16..w*16+15; 4 n-tiles x 2 mats, K=64
    f32x4 acc0[4] = {{0,0,0,0},{0,0,0,0},{0,0,0,0},{0,0,0,0}};
    f32x4 acc1[4] = {{0,0,0,0},{0,0,0,0},{0,0,0,0},{0,0,0,0}};
    #pragma unroll
    for (int kt = 0; kt < 2; ++kt) {
        bf16x8 af = *(const bf16x8*)&sX[(w * 16 + lane15) * SXW + kt * 32 + quad * 8];
        #pragma unroll
        for (int nt = 0; nt < 4; ++nt) {
            bf16x8 b0 = *(const bf16x8*)&sWb[0][(nt * 16 + lane15) * SXW + kt * 32 + quad * 8];
            acc0[nt] = __builtin_amdgcn_mfma_f32_16x16x32_bf16(af, b0, acc0[nt], 0, 0, 0);
            bf16x8 b1 = *(const bf16x8*)&sWb[1][(nt * 16 + lane15) * SXW + kt * 32 + quad * 8];
            acc1[nt] = __builtin_amdgcn_mfma_f32_16x16x32_bf16(af, b1, acc1[nt], 0, 0, 0);
        }
    }

    // epilogue: D[m = quad*4+r][f = nt*16+lane15]; sT <- h1, gN <- h0-h1, scores
    float a1v[4], a2v[4];
    #pragma unroll
    for (int nt = 0; nt < 4; ++nt) {
        a1v[nt] = a[nt * 16 + lane15];
        a2v[nt] = a[64 + nt * 16 + lane15];
    }
    float p1[4] = {0, 0, 0, 0}, p2[4] = {0, 0, 0, 0};
    unsigned short* gNu = (unsigned short*)gN + (size_t)b * 32768 + (size_t)n0 * 64;
    #pragma unroll
    for (int nt = 0; nt < 4; ++nt) {
        #pragma unroll
        for (int r = 0; r < 4; ++r) {
            int nlr = w * 16 + quad * 4 + r;
            int f   = nt * 16 + lane15;
            float h0v = acc0[nt][r], h1v = acc1[nt][r];
            __hip_bfloat16 hb = __float2bfloat16(h1v);
            sT[f * 66 + nlr] = *(unsigned short*)&hb;
            __hip_bfloat16 gb16 = __float2bfloat16(h0v - h1v);
            gNu[(size_t)nlr * 64 + f] = *(unsigned short*)&gb16;
            float hs = h0v + h1v;
            p1[r] = fmaf(hs, a1v[nt], p1[r]);
            p2[r] = fmaf(hs, a2v[nt], p2[r]);
        }
    }
    // packed butterfly: 4-stage chain, 8 independent adds per stage
    #pragma unroll
    for (int o = 1; o < 16; o <<= 1) {
        #pragma unroll
        for (int r = 0; r < 4; ++r) {
            p1[r] += __shfl_xor(p1[r], o, 64);
            p2[r] += __shfl_xor(p2[r], o, 64);
        }
    }
    if (lane15 == 0) {
        #pragma unroll
        for (int r = 0; r < 4; ++r) {
            int row = b * NN + n0 + w * 16 + quad * 4 + r;
            s1[row] = p1[r]; s2[row] = p2[r];
        }
    }
    __syncthreads();
    // h1T: wave w writes f-rows w*16..w*16+15, 128B contiguous
    unsigned short* h1Tu = (unsigned short*)h1T;
    #pragma unroll
    for (int fr = 0; fr < 16; ++fr) {
        int f = w * 16 + fr;
        h1Tu[(size_t)b * 32768 + f * 512 + n0 + lane] = sT[f * 66 + lane];
    }
}

// k2 (round-1 measured-best structure): 2048 blocks, XCD-chunked swizzle. Block =
// (b, 32 rows). bits path (4 MB L2 traffic, not 128 MB adj). Softmax: no max-sub
// (masked -> exact 0); row sums ls[8] + ONE packed 6-stage butterfly. Diag prob
// kept in MFMA (bf16-rounded pi); 8-deep B-frag register prefetch in measured-best
// position; g scalars prefetched before MFMA; out via NON-TEMPORAL stores
// (write-only; keeps h1T/bits in L2).
__global__ __launch_bounds__(256, 4) void k2_att(
    const unsigned char* __restrict__ adjbits,
    const float* __restrict__ bias,
    const __hip_bfloat16* __restrict__ h1T,
    const __hip_bfloat16* __restrict__ gN,
    const float* __restrict__ s1, const float* __restrict__ s2,
    float* __restrict__ out)
{
    __shared__ __align__(16) __hip_bfloat16 sPb[32 * SPB];   // 34.3 KB
    __shared__ float sInv[32], sPi[32];
    int tid = threadIdx.x, w = tid >> 6, lane = tid & 63;
    int F = blockIdx.x;
    int work = (F & 7) * 256 + (F >> 3);     // bijective (2048 % 8 == 0)
    int b = work >> 4;
    int i0 = (work & 15) << 5;

    const float* s2b = s2 + (size_t)b * NN;
    float4 q0 = *(const float4*)(s2b + lane * 8);
    float4 q1 = *(const float4*)(s2b + lane * 8 + 4);
    float sv[8] = {q0.x, q0.y, q0.z, q0.w, q1.x, q1.y, q1.z, q1.w};

    // prefetch the 8 s1 row-scalars for this wave (contiguous 32 B)
    const float* s1p = s1 + (size_t)b * NN + i0 + 8 * w;
    float4 sA = *(const float4*)(s1p + 0);
    float4 sB = *(const float4*)(s1p + 4);
    float s1r[8] = {sA.x, sA.y, sA.z, sA.w, sB.x, sB.y, sB.z, sB.w};

    float ls[8];
    #pragma unroll
    for (int r2 = 0; r2 < 8; ++r2) {
        int r = 8 * w + r2;
        int i = i0 + r;
        float s1i = s1r[r2];
        unsigned mb = adjbits[(size_t)i * 64 + lane];
        float p[8], l = 0.f;
        #pragma unroll
        for (int t = 0; t < 8; ++t) {
            float s = s1i + sv[t];
            s = fmaxf(s, ALPHA_ * s);             // leaky-relu
            float e = (mb & (1u << t)) ? s : NEG_INF_;
            p[t] = __expf(e);                     // no max-sub; mask -> exact 0
            l += p[t];
        }
        ls[r2] = l;
        union { bf16x8 v; __hip_bfloat16 h[8]; } pk;
        #pragma unroll
        for (int t = 0; t < 8; ++t) pk.h[t] = __float2bfloat16(p[t]);
        if (lane == (i >> 3)) sPi[r] = __bfloat162float(pk.h[r2]);  // rounded pi
        *(bf16x8*)&sPb[r * SPB + lane * 8] = pk.v;
    }
    // ONE packed butterfly: 6-stage chain, 8 independent adds per stage
    #pragma unroll
    for (int o = 32; o > 0; o >>= 1) {
        #pragma unroll
        for (int r2 = 0; r2 < 8; ++r2) ls[r2] += __shfl_xor(ls[r2], o, 64);
    }
    if (lane == 0) {
        #pragma unroll
        for (int r2 = 0; r2 < 8; ++r2) sInv[8 * w + r2] = 1.f / ls[r2];
    }
    __syncthreads();

    // MFMA: wave w = f-tile; two m-tiles (rows 0..15, 16..31) share B-frags
    int lane15 = lane & 15, quad = lane >> 4;
    int n0w = w * 16;
    int f = n0w + lane15;
    float biasf = bias[f];
    const __hip_bfloat16* bptr = h1T + (size_t)b * 32768 + (size_t)f * 512 + quad * 8;
    const __hip_bfloat16* aptr0 = &sPb[lane15 * SPB + quad * 8];
    const __hip_bfloat16* aptr1 = &sPb[(16 + lane15) * SPB + quad * 8];

    // early g loads: issue before MFMA so L2/HBM latency hides under compute
    const unsigned short* gb = (const unsigned short*)gN + (size_t)b * 32768 + f;
    unsigned short gvw[8];
    #pragma unroll
    for (int t = 0; t < 2; ++t) {
        #pragma unroll
        for (int r = 0; r < 4; ++r)
            gvw[t * 4 + r] = gb[(size_t)(i0 + t * 16 + quad * 4 + r) * 64];
    }

    f32x4 acc0 = {0, 0, 0, 0}, acc1 = {0, 0, 0, 0};
    bf16x8 bfr[8];
    #pragma unroll
    for (int half = 0; half < 2; ++half) {
        #pragma unroll
        for (int g = 0; g < 8; ++g)
            bfr[g] = *(const bf16x8*)(bptr + (half * 8 + g) * 32);
        #pragma unroll
        for (int g = 0; g < 8; ++g) {
            int kt = half * 8 + g;
            bf16x8 a0 = *(const bf16x8*)(aptr0 + kt * 32);
            acc0 = __builtin_amdgcn_mfma_f32_16x16x32_bf16(a0, bfr[g], acc0, 0, 0, 0);
            bf16x8 a1 = *(const bf16x8*)(aptr1 + kt * 32);
            acc1 = __builtin_amdgcn_mfma_f32_16x16x32_bf16(a1, bfr[g], acc1, 0, 0, 0);
        }
    }

    // Epilogue: out = (acc + pi*g)*inv + bias  (write-only -> non-temporal)
    #pragma unroll
    for (int t = 0; t < 2; ++t) {
        f32x4 ac = t ? acc1 : acc0;
        #pragma unroll
        for (int r = 0; r < 4; ++r) {
            int m = t * 16 + quad * 4 + r;
            int i = i0 + m;
            float gvf = bfs2f(gvw[t * 4 + r]);
            float inv = sInv[m], pi = sPi[m];
            float v = (ac[r] + pi * gvf) * inv + biasf;
            __builtin_nontemporal_store(v, &out[((size_t)b * NN + i) * 64 + f]);
        }
    }
}

extern "C" void kernel_launch(void* const* d_in, const int* in_sizes, int n_in,
                              void* d_out, int out_size, void* d_ws, size_t ws_size,
                              hipStream_t stream) {
    const void* p_x = nullptr; const void* p_adj = nullptr; const void* p_W = nullptr;
    const void* p_a = nullptr; const void* p_bias = nullptr;
    for (int k = 0; k < n_in; ++k) {
        switch (in_sizes[k]) {
            case 128 * 512 * 64: p_x    = d_in[k]; break;
            case 512 * 512:      p_adj  = d_in[k]; break;
            case 2 * 64 * 64:    p_W    = d_in[k]; break;
            case 2 * 64:         p_a    = d_in[k]; break;
            case 64:             p_bias = d_in[k]; break;
        }
    }
    const float* x    = (const float*)p_x;
    const int*   adj  = (const int*)p_adj;
    const float* W    = (const float*)p_W;
    const float* a    = (const float*)p_a;
    const float* bias = (const float*)p_bias;
    float* out = (float*)d_out;

    // ws (16.5 MB): h1T bf16 8MB | gN bf16 8MB | s1 256KB | s2 256KB | bits 32KB
    __hip_bfloat16* h1T = (__hip_bfloat16*)d_ws;
    __hip_bfloat16* gN  = h1T + 4194304;
    float* s1 = (float*)(gN + 4194304);
    float* s2 = s1 + 65536;
    unsigned char* bits = (unsigned char*)(s2 + 65536);

    k1_proj<<<dim3(BB * 8), 256, 0, stream>>>(x, W, a, adj, bits, h1T, gN, s1, s2);
    k2_att<<<dim3(BB * NN / 32), 256, 0, stream>>>(bits, bias, h1T, gN, s1, s2, out);
}